// Round 1
// baseline (641.095 us; speedup 1.0000x reference)
//
#include <hip/hip_runtime.h>

#define B_ 4
#define C_ 512
#define H_ 96
#define W_ 320
#define D_ 48

#define CHUNK 8          // channels staged per LDS chunk
#define NCH (C_/CHUNK)   // 64 chunk iterations
#define TW 40            // thread groups along w  (40*8 = 320 = full row)
#define TD 6             // thread groups along d  (6*8  = 48 = full D)
#define NW 8             // per-thread outputs along w
#define ND 8             // per-thread outputs along d
#define NT (TW*TD)       // 240 threads (3.75 waves)
#define ROWF 704         // floats per channel-row in LDS: L[0,320) R[320,688) pad[688,704)
#define RB 320           // R sub-row base (floats); R row = 48 zero-prefix + 320 data
#define F4PC 1280        // float4s staged per chunk: 8 rows x (80 L + 80 R)
#define SIT 6            // staging iterations: ceil(1280/240)

// XOR-swizzle 16B granules within 128B blocks keyed by block index (T2-style).
// Fixes the 4-way bank conflict from the 32B lane stride of compute reads.
// Closed within each 32-float block (key<<2 < 32), so any 32-float-aligned
// region maps onto itself; the zero-prefix range [320,368) is also closed
// (proved per 16-float subgroup), so prefix zeroing can write linearly.
__device__ __forceinline__ int swzf(int f) {
  return f ^ (((f >> 5) & 7) << 2);
}

__global__ __launch_bounds__(NT)
void cost_volume_kernel(const float* __restrict__ Lp,
                        const float* __restrict__ Rp,
                        float* __restrict__ out) {
  __shared__ float lds[2][CHUNK][ROWF];
  float* ldsf = &lds[0][0][0];
  const int tid = threadIdx.x;
  const int b  = blockIdx.x / H_;
  const int h  = blockIdx.x % H_;
  const int wt = tid % TW;         // w group: w = 8*wt + iw
  const int dt = tid / TW;         // d group: d = 8*dt + id

  // Zero the 48-float masking prefix of every R sub-row (both buffers).
  // Prefix stays zero forever: staging only writes [0,320) and [368,688).
  if (tid < 2*CHUNK*12) {
    const int row = tid / 12, k4 = tid % 12;
    *(float4*)(ldsf + row*ROWF + RB + 4*k4) = make_float4(0.f, 0.f, 0.f, 0.f);
  }

  // Staging descriptors: flat float4 index f -> (channel-row c, slot r).
  // r in [0,80) = L float4s, r in [80,160) = R float4s. Constant per thread.
  const float* sp[SIT];
  int dstf[SIT];
  bool act[SIT];
#pragma unroll
  for (int it = 0; it < SIT; ++it) {
    int f = tid + NT*it;
    act[it] = (f < F4PC);
    int fc = act[it] ? f : 0;
    int c = fc / 160;
    int r = fc % 160;
    bool isl = (r < 80);
    int col = isl ? 4*r : 4*(r-80);
    sp[it] = (isl ? Lp : Rp) + ((size_t)(b*C_ + c)*H_ + h)*W_ + col;
    int local = isl ? (4*r) : (RB + 48 + 4*(r-80));
    dstf[it] = c*ROWF + swzf(local);
  }

  // Per-thread swizzled LDS read offsets (identical for every row/buffer).
  // R window: floats [jb, jb+16) of the R sub-row; used index = 8+iw-id in [1,15].
  // jb = 8*(wt-dt)+40 is a multiple of 8 -> 16B aligned, uniform across lanes.
  const int jb = 8*(wt - dt) + 40;                 // [0, 352]
  const int o_r0 = swzf(RB + jb +  0);
  const int o_r1 = swzf(RB + jb +  4);
  const int o_r2 = swzf(RB + jb +  8);
  const int o_r3 = swzf(RB + jb + 12);
  const int o_l0 = swzf(8*wt + 0);
  const int o_l1 = swzf(8*wt + 4);

  float acc[NW][ND];
#pragma unroll
  for (int i = 0; i < NW; ++i)
#pragma unroll
    for (int j = 0; j < ND; ++j) acc[i][j] = 0.f;

  float4 sreg[SIT];
  // Prologue: stage chunk 0 into buffer 0.
#pragma unroll
  for (int it = 0; it < SIT; ++it) if (act[it]) sreg[it] = *(const float4*)sp[it];
#pragma unroll
  for (int it = 0; it < SIT; ++it) sp[it] += (size_t)CHUNK*H_*W_;
#pragma unroll
  for (int it = 0; it < SIT; ++it) if (act[it]) *(float4*)(ldsf + dstf[it]) = sreg[it];

  for (int k = 0; k < NCH; ++k) {
    if (k < NCH-1) {
      // T14 async-split: issue next chunk's global loads BEFORE compute;
      // HBM latency hides under this chunk's ds_read+FMA work.
#pragma unroll
      for (int it = 0; it < SIT; ++it) if (act[it]) sreg[it] = *(const float4*)sp[it];
#pragma unroll
      for (int it = 0; it < SIT; ++it) sp[it] += (size_t)CHUNK*H_*W_;
    }
    __syncthreads();                         // buf (k&1) writes visible
    const float* base = ldsf + (k & 1)*(CHUNK*ROWF);
#pragma unroll
    for (int cc = 0; cc < CHUNK; ++cc) {
      const float* row = base + cc*ROWF;
      float4 r0 = *(const float4*)(row + o_r0);
      float4 r1 = *(const float4*)(row + o_r1);
      float4 r2 = *(const float4*)(row + o_r2);
      float4 r3 = *(const float4*)(row + o_r3);
      float4 l0 = *(const float4*)(row + o_l0);
      float4 l1 = *(const float4*)(row + o_l1);
      const float rr[16] = {r0.x,r0.y,r0.z,r0.w, r1.x,r1.y,r1.z,r1.w,
                            r2.x,r2.y,r2.z,r2.w, r3.x,r3.y,r3.z,r3.w};
      const float ll[8]  = {l0.x,l0.y,l0.z,l0.w, l1.x,l1.y,l1.z,l1.w};
#pragma unroll
      for (int iw = 0; iw < NW; ++iw)
#pragma unroll
        for (int id = 0; id < ND; ++id)
          acc[iw][id] = fmaf(ll[iw], rr[8 + iw - id], acc[iw][id]);
    }
    if (k < NCH-1) {
      __syncthreads();                       // all reads of buf ((k+1)&1) done
      float* wb = ldsf + ((k+1) & 1)*(CHUNK*ROWF);
#pragma unroll
      for (int it = 0; it < SIT; ++it) if (act[it]) *(float4*)(wb + dstf[it]) = sreg[it];
    }
  }

  // Epilogue: mean (exact /512) + coalesced float4 stores.
  const float scale = 1.0f / (float)C_;
  const size_t obase = (size_t)b*D_*H_*W_ + (size_t)h*W_ + (size_t)wt*NW;
#pragma unroll
  for (int id = 0; id < ND; ++id) {
    const int d = dt*ND + id;
    float4 v0 = make_float4(acc[0][id]*scale, acc[1][id]*scale,
                            acc[2][id]*scale, acc[3][id]*scale);
    float4 v1 = make_float4(acc[4][id]*scale, acc[5][id]*scale,
                            acc[6][id]*scale, acc[7][id]*scale);
    float* o = out + obase + (size_t)d*H_*W_;
    *(float4*)o       = v0;
    *(float4*)(o + 4) = v1;
  }
}

extern "C" void kernel_launch(void* const* d_in, const int* in_sizes, int n_in,
                              void* d_out, int out_size, void* d_ws, size_t ws_size,
                              hipStream_t stream) {
  const float* left  = (const float*)d_in[0];
  const float* right = (const float*)d_in[1];
  float* outp = (float*)d_out;
  cost_volume_kernel<<<dim3(B_*H_), dim3(NT), 0, stream>>>(left, right, outp);
}

// Round 2
// 383.801 us; speedup vs baseline: 1.6704x; 1.6704x over previous
//
#include <hip/hip_runtime.h>

#define B_ 4
#define C_ 512
#define H_ 96
#define W_ 320
#define D_ 48
#define HW_ (H_*W_)
#define NOUT (B_*D_*H_*W_)   // 5,898,240 outputs

#define SPLITS 2
#define CPS (C_/SPLITS)      // 256 channels per block
#define CHUNK 8              // channel rows staged per LDS buffer
#define NCH (CPS/CHUNK)      // 32 chunk iterations
#define TW 40                // w groups: w = 8*wt + iw
#define TD 6                 // d groups: d = 8*dt + id
#define NW 8
#define ND 8
#define NT (TW*TD)           // 240 threads
#define RS 688               // bf16 elems per row: L[0,320) | zeros[320,368) | R[368,688)
#define F8PC 640             // float8 staging units per chunk: 8 rows x (40 L + 40 R)
#define SIT 3                // ceil(640/240)

// fp32 -> bf16 round-to-nearest-even, and pack/unpack helpers.
__device__ __forceinline__ unsigned bf16rne(float f) {
  unsigned u = __float_as_uint(f);
  return (u + 0x7FFFu + ((u >> 16) & 1u)) >> 16;
}
__device__ __forceinline__ int pk2(float lo, float hi) {
  return (int)(bf16rne(lo) | (bf16rne(hi) << 16));
}
__device__ __forceinline__ float blo(int u) { return __uint_as_float(((unsigned)u) << 16); }
__device__ __forceinline__ float bhi(int u) { return __uint_as_float(((unsigned)u) & 0xFFFF0000u); }

__global__ __launch_bounds__(NT)
void cost_volume_kernel(const float* __restrict__ Lp,
                        const float* __restrict__ Rp,
                        float* __restrict__ dst,   // partial base (2*NOUT) or out (atomic)
                        int atom) {
  __shared__ __align__(16) ushort lds[2 * CHUNK * RS];   // 22 KB, double-buffered
  const int tid = threadIdx.x;
  const int bid = blockIdx.x;
  const int split = bid & 1;         // channel half
  const int bh = bid >> 1;
  const int b = bh / H_, h = bh % H_;
  const int wt = tid % TW, dt = tid / TW;
  const int c0 = split * CPS;

  // Zero the 48-elem masking prefix of every row (both buffers): 16 rows x 6 int4.
  // Staging writes only [0,320) and [368,688) so the prefix stays zero.
  if (tid < 96) {
    const int row = tid / 6, g = tid % 6;
    *(int4*)(lds + row * RS + 320 + 8 * g) = make_int4(0, 0, 0, 0);
  }

  // Staging descriptors: float8 unit f -> (channel-row c, slot r). r<40 = L, else R.
  const float* sp[SIT];
  int dste[SIT];
  bool act[SIT];
#pragma unroll
  for (int it = 0; it < SIT; ++it) {
    const int f = tid + NT * it;
    act[it] = (f < F8PC);
    const int fc = act[it] ? f : 0;
    const int c = fc / 80, r = fc % 80;
    const bool isl = (r < 40);
    const int col = 8 * (isl ? r : r - 40);
    sp[it] = (isl ? Lp : Rp) + ((size_t)(b * C_ + c0 + c) * H_ + h) * W_ + col;
    dste[it] = c * RS + (isl ? 8 * r : 368 + 8 * (r - 40));
  }

  // Compute-read element offsets (bf16 units). One granule per lane-step -> conflict-free.
  const int jb = 8 * (wt - dt) + 40;     // [0, 352], multiple of 8

  float acc[NW][ND];
#pragma unroll
  for (int i = 0; i < NW; ++i)
#pragma unroll
    for (int j = 0; j < ND; ++j) acc[i][j] = 0.f;

  float4 sa[SIT], sb[SIT];

#define SLOAD() \
  _Pragma("unroll") for (int it = 0; it < SIT; ++it) if (act[it]) { \
    sa[it] = *(const float4*)sp[it]; sb[it] = *(const float4*)(sp[it] + 4); } \
  _Pragma("unroll") for (int it = 0; it < SIT; ++it) sp[it] += (size_t)CHUNK * HW_;

#define SWRITE(buf) \
  _Pragma("unroll") for (int it = 0; it < SIT; ++it) if (act[it]) { \
    int4 pk; pk.x = pk2(sa[it].x, sa[it].y); pk.y = pk2(sa[it].z, sa[it].w); \
    pk.z = pk2(sb[it].x, sb[it].y); pk.w = pk2(sb[it].z, sb[it].w); \
    *(int4*)(lds + (buf) * (CHUNK * RS) + dste[it]) = pk; }

  // Prologue: stage chunk 0 into buffer 0.
  SLOAD();
  SWRITE(0);

  for (int k = 0; k < NCH; ++k) {
    if (k < NCH - 1) {
      SLOAD();                       // T14: issue next chunk's HBM loads before compute
    }
    __syncthreads();                 // buf (k&1) writes (and prefix zeros) visible
    const ushort* base = lds + (k & 1) * (CHUNK * RS);
#pragma unroll
    for (int cc = 0; cc < CHUNK; ++cc) {
      const ushort* row = base + cc * RS;
      const int4 lv  = *(const int4*)(row + 8 * wt);
      const int4 rv0 = *(const int4*)(row + 320 + jb);
      const int4 rv1 = *(const int4*)(row + 328 + jb);
      const float ll[8] = { blo(lv.x), bhi(lv.x), blo(lv.y), bhi(lv.y),
                            blo(lv.z), bhi(lv.z), blo(lv.w), bhi(lv.w) };
      const float rr[16] = { blo(rv0.x), bhi(rv0.x), blo(rv0.y), bhi(rv0.y),
                             blo(rv0.z), bhi(rv0.z), blo(rv0.w), bhi(rv0.w),
                             blo(rv1.x), bhi(rv1.x), blo(rv1.y), bhi(rv1.y),
                             blo(rv1.z), bhi(rv1.z), blo(rv1.w), bhi(rv1.w) };
#pragma unroll
      for (int iw = 0; iw < NW; ++iw)
#pragma unroll
        for (int id = 0; id < ND; ++id)
          acc[iw][id] = fmaf(ll[iw], rr[8 + iw - id], acc[iw][id]);
    }
    if (k < NCH - 1) {
      __syncthreads();               // all reads of buf ((k+1)&1) done
      SWRITE((k + 1) & 1);
    }
  }

  // Epilogue
  const float scale = 1.0f / (float)C_;
  const size_t ob = (size_t)b * (D_ * HW_) + (size_t)h * W_ + wt * NW;
  if (!atom) {
    float* p0 = dst + (size_t)split * NOUT;
#pragma unroll
    for (int id = 0; id < ND; ++id) {
      const int d = dt * ND + id;
      float4 v0 = make_float4(acc[0][id] * scale, acc[1][id] * scale,
                              acc[2][id] * scale, acc[3][id] * scale);
      float4 v1 = make_float4(acc[4][id] * scale, acc[5][id] * scale,
                              acc[6][id] * scale, acc[7][id] * scale);
      float* o = p0 + ob + (size_t)d * HW_;
      *(float4*)o = v0;
      *(float4*)(o + 4) = v1;
    }
  } else {
#pragma unroll
    for (int id = 0; id < ND; ++id) {
      const int d = dt * ND + id;
      float* o = dst + ob + (size_t)d * HW_;
#pragma unroll
      for (int iw = 0; iw < NW; ++iw) atomicAdd(o + iw, acc[iw][id] * scale);
    }
  }
}

__global__ __launch_bounds__(256)
void reduce2_kernel(const float4* __restrict__ a, const float4* __restrict__ b,
                    float4* __restrict__ o, int n4) {
  const int i = blockIdx.x * 256 + threadIdx.x;
  if (i < n4) {
    const float4 x = a[i], y = b[i];
    o[i] = make_float4(x.x + y.x, x.y + y.y, x.z + y.z, x.w + y.w);
  }
}

extern "C" void kernel_launch(void* const* d_in, const int* in_sizes, int n_in,
                              void* d_out, int out_size, void* d_ws, size_t ws_size,
                              hipStream_t stream) {
  const float* left  = (const float*)d_in[0];
  const float* right = (const float*)d_in[1];
  float* outp = (float*)d_out;
  const size_t need = (size_t)2 * NOUT * sizeof(float);
  if (ws_size >= need) {
    float* ws = (float*)d_ws;
    cost_volume_kernel<<<dim3(B_ * H_ * SPLITS), dim3(NT), 0, stream>>>(left, right, ws, 0);
    const int n4 = NOUT / 4;
    reduce2_kernel<<<dim3(n4 / 256), dim3(256), 0, stream>>>(
        (const float4*)ws, (const float4*)(ws + NOUT), (float4*)outp, n4);
  } else {
    hipMemsetAsync(outp, 0, (size_t)NOUT * sizeof(float), stream);
    cost_volume_kernel<<<dim3(B_ * H_ * SPLITS), dim3(NT), 0, stream>>>(left, right, outp, 1);
  }
}

// Round 3
// 185.755 us; speedup vs baseline: 3.4513x; 2.0662x over previous
//
#include <hip/hip_runtime.h>

#define B_ 4
#define C_ 512
#define H_ 96
#define W_ 320
#define D_ 48
#define HW_ (H_*W_)
#define NOUT (B_*D_*H_*W_)

#define KC 32              // channels per chunk = MFMA K
#define NCHUNK (C_/KC)     // 16
#define LCOLS 160          // L columns per half-row
#define COLS 368           // 160 L + 208 R (48-col halo)
#define CB 64              // bytes per LDS column (32 bf16)
#define BUFB (COLS*CB)     // 23552 B per buffer
#define NT 320             // 5 waves
#define NU (COLS*4)        // 1472 staging units (col, k-granule)
#define SIT 5              // ceil(NU/NT)
#define EPS 168            // epilogue row stride in floats (bank-spread + 16B-aligned)

typedef __attribute__((ext_vector_type(8))) short bf16x8;
typedef __attribute__((ext_vector_type(4))) float f32x4;

__device__ __forceinline__ unsigned bf16rne(float f) {
  unsigned u = __float_as_uint(f);
  return (u + 0x7FFFu + ((u >> 16) & 1u)) >> 16;
}
__device__ __forceinline__ unsigned pk2(float lo, float hi) {
  return bf16rne(lo) | (bf16rne(hi) << 16);
}
// Byte offset of (column, 16B k-granule g) with XOR swizzle.
// Reads (col = 16-aligned base + (lane&15), g = lane>>4): exactly 8 dword
// accesses per bank = the 1KB/wave floor -> conflict-free.
// Writes (64 consecutive cols, fixed g): 8 starts x 8 lanes -> also floor.
__device__ __forceinline__ int swz(int col, int g) {
  return col * CB + (((g ^ (col & 3) ^ ((col >> 2) & 3)) & 3) << 4);
}

__global__ __launch_bounds__(NT)
void cost_volume_mfma(const float* __restrict__ Lp,
                      const float* __restrict__ Rp,
                      float* __restrict__ out) {
  __shared__ __align__(16) char lds[2 * BUFB];   // 47104 B (3 blocks/CU)
  const int tid = threadIdx.x;
  const int bid = blockIdx.x;
  const int half = bid & 1;
  const int bh = bid >> 1;
  const int b = bh / H_, h = bh % H_;
  const int wv = tid >> 6;             // wave 0..4
  const int lc = tid & 15;             // fragment row/col lane index
  const int lg = (tid >> 4) & 3;       // fragment k-granule (l>>4 within wave)
  const int mh0 = 2 * wv;              // local m-tile base within half
  const int m0 = 10 * half + mh0;      // global m-tile of ml=0

  // ---- staging unit descriptors: unit u -> (col = u%COLS, g = u/COLS) ----
  const float* sp[SIT];
  int sdst[SIT];
  bool sact[SIT];
#pragma unroll
  for (int it = 0; it < SIT; ++it) {
    const int u = tid + NT * it;
    bool a = (u < NU);
    const int uc = a ? u : 0;
    const int col = uc % COLS;
    const int g = uc / COLS;
    int x;
    const float* basep;
    if (col < LCOLS) { x = 160 * half + col; basep = Lp; }
    else             { x = (160 * half - 48) + (col - LCOLS); basep = Rp; a = a && (x >= 0); }
    if (x < 0) x = 0;
    sp[it] = basep + ((size_t)(b * C_ + 8 * g) * H_ + h) * W_ + x;
    sdst[it] = swz(col, g);
    sact[it] = a;
  }

  float sreg[SIT][8];

#define SLOAD() \
  _Pragma("unroll") for (int it = 0; it < SIT; ++it) { \
    if (sact[it]) { \
      _Pragma("unroll") for (int kk = 0; kk < 8; ++kk) \
        sreg[it][kk] = sp[it][(size_t)kk * HW_]; \
    } \
    sp[it] += (size_t)KC * HW_; \
  }

#define SWRITE(bb) \
  _Pragma("unroll") for (int it = 0; it < SIT; ++it) if (sact[it]) { \
    uint4 p; \
    p.x = pk2(sreg[it][0], sreg[it][1]); \
    p.y = pk2(sreg[it][2], sreg[it][3]); \
    p.z = pk2(sreg[it][4], sreg[it][5]); \
    p.w = pk2(sreg[it][6], sreg[it][7]); \
    *(uint4*)(lds + (bb) * BUFB + sdst[it]) = p; \
  }

  // ---- fragment LDS offsets (constant across chunks) ----
  const int aoff0 = swz(16 * mh0 + lc, lg);
  const int aoff1 = swz(16 * (mh0 + 1) + lc, lg);
  int boff[5];
  bool bval[5];
#pragma unroll
  for (int dnp = 0; dnp < 5; ++dnp) {
    const int jn = m0 + 1 - dnp;             // n-tile index for this slot
    const int jloc = jn - 10 * half;         // >= -3 -> LDS col >= 160, in-bounds
    boff[dnp] = swz(208 + 16 * jloc + lc, lg);
    bval[dnp] = (jn >= 0);
  }

  f32x4 acc[2][4];
#pragma unroll
  for (int ml = 0; ml < 2; ++ml)
#pragma unroll
    for (int dn = 0; dn < 4; ++dn) acc[ml][dn] = (f32x4){0.f, 0.f, 0.f, 0.f};

  // ---- K loop: T14 issue-early / write-late, double-buffered, 1 barrier/iter ----
  SLOAD();
  SWRITE(0);
  for (int k = 0; k < NCHUNK; ++k) {
    if (k < NCHUNK - 1) { SLOAD(); }
    __syncthreads();
    const char* base = lds + (k & 1) * BUFB;
    const bf16x8 a0 = *(const bf16x8*)(base + aoff0);
    const bf16x8 a1 = *(const bf16x8*)(base + aoff1);
    bf16x8 bf[5];
#pragma unroll
    for (int dnp = 0; dnp < 5; ++dnp)
      if (bval[dnp]) bf[dnp] = *(const bf16x8*)(base + boff[dnp]);
#pragma unroll
    for (int dn = 0; dn < 4; ++dn) {
      if (bval[dn + 1])
        acc[0][dn] = __builtin_amdgcn_mfma_f32_16x16x32_bf16(a0, bf[dn + 1], acc[0][dn], 0, 0, 0);
      if (bval[dn])
        acc[1][dn] = __builtin_amdgcn_mfma_f32_16x16x32_bf16(a1, bf[dn], acc[1][dn], 0, 0, 0);
    }
    if (k < NCHUNK - 1) { SWRITE((k + 1) & 1); }
  }

  // ---- epilogue: transpose through LDS -> coalesced stores ----
  __syncthreads();
  float* ep = (float*)lds;                   // [48][EPS] = 32256 B
#pragma unroll
  for (int e = 0; e < (48 * EPS + NT - 1) / NT; ++e) {
    const int i = tid + NT * e;
    if (i < 48 * EPS) ep[i] = 0.f;
  }
  __syncthreads();
  const float scale = 1.f / 512.f;
#pragma unroll
  for (int ml = 0; ml < 2; ++ml) {
    const int mh = mh0 + ml;
#pragma unroll
    for (int dn = 0; dn < 4; ++dn) {
      const int jn = m0 + ml - dn;
      if (jn >= 0) {
#pragma unroll
        for (int q = 0; q < 4; ++q) {
          const int i = 4 * lg + q;          // C/D row = 4*(lane>>4) + reg
          const int d = 16 * dn + i - lc;    // d = w - j
          if (d >= 0 && d < 48)
            ep[d * EPS + 16 * mh + i] = acc[ml][dn][q] * scale;
        }
      }
    }
  }
  __syncthreads();
  // 48 rows x 40 float4 = 1920 units = 6 per thread, coalesced global stores
#pragma unroll
  for (int e = 0; e < 6; ++e) {
    const int u = tid + NT * e;
    const int d = u / 40, c4 = u % 40;
    const float4 v = *(const float4*)(ep + d * EPS + 4 * c4);
    float* o = out + (((size_t)b * D_ + d) * H_ + h) * W_ + 160 * half + 4 * c4;
    *(float4*)o = v;
  }
}

extern "C" void kernel_launch(void* const* d_in, const int* in_sizes, int n_in,
                              void* d_out, int out_size, void* d_ws, size_t ws_size,
                              hipStream_t stream) {
  const float* left  = (const float*)d_in[0];
  const float* right = (const float*)d_in[1];
  float* outp = (float*)d_out;
  cost_volume_mfma<<<dim3(B_ * H_ * 2), dim3(NT), 0, stream>>>(left, right, outp);
}